// Round 14
// baseline (290.241 us; speedup 1.0000x reference)
//
#include <hip/hip_runtime.h>
#include <hip/hip_bf16.h>

// RGCN (2 relations, d=128, two layers) for MI355X — round 14.
// Aggregate-then-transform, bf16 MFMA GEMM (16x16x32).
//   A[n] = [mean_r0 | mean_r1 | x_n]  (384 bf16, contiguous)
//   out[n] = A[n] @ [W0; W1; root] + bias   (one fused GEMM per layer)
// Round-14 changes:
//  - bucket_build launches only 196 blocks (1/4 of GPU idle). Fused the
//    xstage + Bt-build streaming work INTO the build dispatch (blocks
//    196..547) -> fills the idle CUs, removes xstage/Bt from the serial
//    critical path. prep_bin is now bin-only.

typedef __attribute__((ext_vector_type(8))) short bf16x8;
typedef __attribute__((ext_vector_type(4))) float f32x4;
typedef unsigned short ushort_t;
typedef unsigned int uint_t;

#define BSHIFT 9                      // bucket = dst >> 9 (512 nodes/bucket)
#define SEGB (1 << (BSHIFT + 1))      // 1024 segments per bucket
#define NBMAX 256
#define SLAB 16384                    // records per bucket slab (mean ~8163)
#define CH_PER_THREAD 8
#define CHUNK (256 * CH_PER_THREAD)   // 2048 edges per bin block
#define XSGB 256                      // xstage grid-stride blocks (1024 thr)

#define GBM 256                       // GEMM rows per block
#define KCH 128                       // GEMM k per LDS chunk (3 chunks)
#define LDBE 136                      // LDS B row stride in elements (272 B)

#define ROWB 768                      // bytes per A row (384 bf16)
#define XOFF 512                      // byte offset of x-slot within row

__device__ __forceinline__ ushort_t f2b(float f) {
  union { float f; uint_t u; } v;
  v.f = f;
  uint_t u = v.u;
  return (ushort_t)((u + 0x7FFFu + ((u >> 16) & 1u)) >> 16);  // RNE
}
// acc += pk.lo*sel.lo + pk.hi*sel.hi  (bf16 pairs, f32 accumulate)
__device__ __forceinline__ void dot2acc(float& a, uint_t pk, uint_t sel) {
  asm("v_dot2_f32_bf16 %0, %1, %2, %0" : "+v"(a) : "v"(pk), "v"(sel));
}

// ---------------- bin: packed records -> fixed per-bucket slabs ----------
__global__ __launch_bounds__(256) void bucket_bin(
    const int* __restrict__ ea, const int* __restrict__ eb, int E, int NB,
    int* __restrict__ cursor, uint_t* __restrict__ staging) {
  __shared__ int h[NBMAX];
  __shared__ int bbase[NBMAX];
  __shared__ int lofs[NBMAX];
  __shared__ int sscan[256];
  __shared__ uint_t sval[CHUNK];
  __shared__ int sdst[CHUNK];
  int b = blockIdx.x;
  int t = threadIdx.x;

  for (int i = t; i < NB; i += 256) h[i] = 0;
  __syncthreads();
  int base_i = b * CHUNK + t * CH_PER_THREAD;  // 8 consecutive edges
  int total = 2 * E;
  int srcv[CH_PER_THREAD], dstv[CH_PER_THREAD], relv;
  bool valid8 = false;
  if (base_i + CH_PER_THREAD <= E) {
    int4 s0 = *(const int4*)(ea + base_i);
    int4 s1 = *(const int4*)(ea + base_i + 4);
    int4 d0 = *(const int4*)(ea + E + base_i);
    int4 d1 = *(const int4*)(ea + E + base_i + 4);
    srcv[0]=s0.x; srcv[1]=s0.y; srcv[2]=s0.z; srcv[3]=s0.w;
    srcv[4]=s1.x; srcv[5]=s1.y; srcv[6]=s1.z; srcv[7]=s1.w;
    dstv[0]=d0.x; dstv[1]=d0.y; dstv[2]=d0.z; dstv[3]=d0.w;
    dstv[4]=d1.x; dstv[5]=d1.y; dstv[6]=d1.z; dstv[7]=d1.w;
    relv = 0; valid8 = true;
  } else if (base_i >= E && base_i + CH_PER_THREAD <= total) {
    int off = base_i - E;
    int4 s0 = *(const int4*)(eb + off);
    int4 s1 = *(const int4*)(eb + off + 4);
    int4 d0 = *(const int4*)(eb + E + off);
    int4 d1 = *(const int4*)(eb + E + off + 4);
    srcv[0]=s0.x; srcv[1]=s0.y; srcv[2]=s0.z; srcv[3]=s0.w;
    srcv[4]=s1.x; srcv[5]=s1.y; srcv[6]=s1.z; srcv[7]=s1.w;
    dstv[0]=d0.x; dstv[1]=d0.y; dstv[2]=d0.z; dstv[3]=d0.w;
    dstv[4]=d1.x; dstv[5]=d1.y; dstv[6]=d1.z; dstv[7]=d1.w;
    relv = 1; valid8 = true;
  }
  uint_t val[CH_PER_THREAD];
  short bktv[CH_PER_THREAD];
  short rj[CH_PER_THREAD];
  if (valid8) {
#pragma unroll
    for (int j = 0; j < CH_PER_THREAD; ++j) {
      int seg = dstv[j] * 2 + relv;
      int bkt = seg >> (BSHIFT + 1);
      val[j] = ((uint_t)srcv[j] << 10) | (uint_t)(seg & (SEGB - 1));
      bktv[j] = (short)bkt;
      rj[j] = (short)atomicAdd(&h[bkt], 1);
    }
  } else {
#pragma unroll
    for (int j = 0; j < CH_PER_THREAD; ++j) {
      int i = base_i + j;
      if (i < total) {
        int src, dst, rel;
        if (i < E) { src = ea[i];     dst = ea[E + i]; rel = 0; }
        else       { src = eb[i - E]; dst = eb[i];     rel = 1; }
        int seg = dst * 2 + rel;
        int bkt = seg >> (BSHIFT + 1);
        val[j] = ((uint_t)src << 10) | (uint_t)(seg & (SEGB - 1));
        bktv[j] = (short)bkt;
        rj[j] = (short)atomicAdd(&h[bkt], 1);
      } else {
        bktv[j] = -1;
      }
    }
  }
  __syncthreads();
  {
    int v = (t < NB) ? h[t] : 0;
    sscan[t] = v;
    __syncthreads();
    for (int off = 1; off < 256; off <<= 1) {
      int tmp = (t >= off) ? sscan[t - off] : 0;
      __syncthreads();
      sscan[t] += tmp;
      __syncthreads();
    }
    if (t < NB) {
      lofs[t] = sscan[t] - v;
      bbase[t] = v ? t * SLAB + atomicAdd(&cursor[t], v) : 0;
    }
  }
  __syncthreads();
#pragma unroll
  for (int j = 0; j < CH_PER_THREAD; ++j) {
    if (!valid8 && bktv[j] < 0) continue;
    int bkt = bktv[j];
    int pos = lofs[bkt] + rj[j];
    sval[pos] = val[j];
    sdst[pos] = bbase[bkt] + rj[j];
  }
  __syncthreads();
  int nrec = 2 * E - b * CHUNK;
  if (nrec > CHUNK) nrec = CHUNK;
  for (int i = t; i < nrec; i += 256)
    staging[sdst[i]] = sval[i];
}

// ---------------- build_fused: per-bucket sort + Bt build + xstage --------
// blocks [0,NB): bucket sort; [NB,NB+96): Bt build; [NB+96,..): xstage.
__global__ __launch_bounds__(1024) void build_fused(
    const uint_t* __restrict__ staging, const int* __restrict__ cursor,
    int* __restrict__ csr, int* __restrict__ offs,
    int* __restrict__ ends, int nseg, int NB,
    const float* __restrict__ W1, const float* __restrict__ root1,
    const float* __restrict__ W2, const float* __restrict__ root2,
    ushort_t* __restrict__ Bt1, ushort_t* __restrict__ Bt2,
    const float* __restrict__ x, ushort_t* __restrict__ aggbuf1, int N) {
  __shared__ int scnt[SEGB];
  __shared__ int sexcl[SEGB];
  __shared__ int sdata[SEGB];
  int b = blockIdx.x;
  int t = threadIdx.x;

  if (b < NB) {
    // ---- per-bucket seg hist + scan + scatter
    int base = b * SLAB;
    int ne = cursor[b];
    int seg0 = b << (BSHIFT + 1);
    scnt[t] = 0;
    __syncthreads();
    const uint_t* st = staging + base;
    uint_t rec[16];
    short rk[16];
#pragma unroll
    for (int k = 0; k < 4; ++k) {
      int i = (t + k * 1024) * 4;
      if (i + 4 <= ne) {
        uint4 v = *(const uint4*)(st + i);
        rec[k * 4 + 0] = v.x;
        rec[k * 4 + 1] = v.y;
        rec[k * 4 + 2] = v.z;
        rec[k * 4 + 3] = v.w;
#pragma unroll
        for (int j = 0; j < 4; ++j)
          rk[k * 4 + j] = (short)atomicAdd(&scnt[rec[k * 4 + j] & (SEGB - 1)], 1);
      } else {
#pragma unroll
        for (int j = 0; j < 4; ++j) {
          int i2 = i + j;
          if (i2 < ne) {
            uint_t v = st[i2];
            rec[k * 4 + j] = v;
            rk[k * 4 + j] = (short)atomicAdd(&scnt[v & (SEGB - 1)], 1);
          } else {
            rec[k * 4 + j] = 0xffffffffu;
          }
        }
      }
    }
    __syncthreads();
    int c = scnt[t];
    sdata[t] = c;
    __syncthreads();
    for (int off = 1; off < 1024; off <<= 1) {
      int tmp = (t >= off) ? sdata[t - off] : 0;
      __syncthreads();
      sdata[t] += tmp;
      __syncthreads();
    }
    int excl = sdata[t] - c;
    sexcl[t] = excl;
    {
      int g = seg0 + t;
      if (g < nseg) { offs[g] = base + excl; ends[g] = base + excl + c; }
    }
    __syncthreads();
#pragma unroll
    for (int k = 0; k < 16; ++k) {
      if (rec[k] != 0xffffffffu) {
        int seg = (int)(rec[k] & (SEGB - 1));
        int src = (int)(rec[k] >> 10);
        csr[base + sexcl[seg] + rk[k]] = src * ROWB + XOFF;  // pre-scaled bytes
      }
    }
  } else if (b < NB + 96) {
    // ---- Bt build: 98304 elems over 96 blocks x 1024 threads
    int flat = (b - NB) * 1024 + t;
    int which = flat >= 49152;
    int idx = flat - which * 49152;
    int c = idx / 384;
    int k = idx - c * 384;
    const float* W = which ? W2 : W1;
    const float* root = which ? root2 : root1;
    ushort_t* Bt = which ? Bt2 : Bt1;
    float v = (k < 256) ? W[(size_t)k * 128 + c] : root[(size_t)(k - 256) * 128 + c];
    Bt[(size_t)c * 384 + k] = f2b(v);
  } else {
    // ---- xstage: grid-stride, 16 lanes per row, uint4 per lane
    int idx = (b - NB - 96) * 1024 + t;
    int tot = N * 16;
    int step = XSGB * 1024;
    for (; idx < tot; idx += step) {
      int n = idx >> 4, tq = idx & 15;
      float4 a = *(const float4*)(x + (size_t)n * 128 + tq * 8);
      float4 c = *(const float4*)(x + (size_t)n * 128 + tq * 8 + 4);
      uint4 o;
      o.x = (uint_t)f2b(a.x) | ((uint_t)f2b(a.y) << 16);
      o.y = (uint_t)f2b(a.z) | ((uint_t)f2b(a.w) << 16);
      o.z = (uint_t)f2b(c.x) | ((uint_t)f2b(c.y) << 16);
      o.w = (uint_t)f2b(c.z) | ((uint_t)f2b(c.w) << 16);
      *(uint4*)(aggbuf1 + (size_t)n * 384 + 256 + tq * 8) = o;
    }
  }
}

// ---------------- aggregation: one wave per segment, quarter-wave per edge --
// csr entries are byte offsets of the source row's x-slot. dot2 accumulate.
__global__ __launch_bounds__(256) void agg_kernel(
    const char* __restrict__ xbc,      // aggbuf base (bytes)
    const int* __restrict__ csr,
    const int* __restrict__ offs, const int* __restrict__ ends,
    ushort_t* __restrict__ agg, int nseg) {
  int wid = (blockIdx.x * blockDim.x + threadIdx.x) >> 6;
  if (wid >= nseg) return;
  int lane = threadIdx.x & 63;
  int q = lane >> 4;
  int t = lane & 15;
  int beg = offs[wid], end = ends[wid];
  const uint_t sel_lo = 0x00003F80u;   // bf16 (1.0, 0.0)
  const uint_t sel_hi = 0x3F800000u;   // bf16 (0.0, 1.0)

  float acc[8];
#pragma unroll
  for (int j = 0; j < 8; ++j) acc[j] = 0.f;

  const char* xt = xbc + t * 16;
  int e = beg + q;
  for (; e + 4 < end; e += 8) {
    int o0 = csr[e];
    int o1 = csr[e + 4];
    uint4 v0 = *(const uint4*)(xt + o0);
    uint4 v1 = *(const uint4*)(xt + o1);
    dot2acc(acc[0], v0.x, sel_lo); dot2acc(acc[1], v0.x, sel_hi);
    dot2acc(acc[2], v0.y, sel_lo); dot2acc(acc[3], v0.y, sel_hi);
    dot2acc(acc[4], v0.z, sel_lo); dot2acc(acc[5], v0.z, sel_hi);
    dot2acc(acc[6], v0.w, sel_lo); dot2acc(acc[7], v0.w, sel_hi);
    dot2acc(acc[0], v1.x, sel_lo); dot2acc(acc[1], v1.x, sel_hi);
    dot2acc(acc[2], v1.y, sel_lo); dot2acc(acc[3], v1.y, sel_hi);
    dot2acc(acc[4], v1.z, sel_lo); dot2acc(acc[5], v1.z, sel_hi);
    dot2acc(acc[6], v1.w, sel_lo); dot2acc(acc[7], v1.w, sel_hi);
  }
  if (e < end) {
    int o0 = csr[e];
    uint4 v0 = *(const uint4*)(xt + o0);
    dot2acc(acc[0], v0.x, sel_lo); dot2acc(acc[1], v0.x, sel_hi);
    dot2acc(acc[2], v0.y, sel_lo); dot2acc(acc[3], v0.y, sel_hi);
    dot2acc(acc[4], v0.z, sel_lo); dot2acc(acc[5], v0.z, sel_hi);
    dot2acc(acc[6], v0.w, sel_lo); dot2acc(acc[7], v0.w, sel_hi);
  }

#pragma unroll
  for (int j = 0; j < 8; ++j) {
    acc[j] += __shfl_xor(acc[j], 16);
    acc[j] += __shfl_xor(acc[j], 32);
  }

  int c = end - beg;
  float inv = 1.0f / (float)(c > 1 ? c : 1);
  if (q == 0) {
    uint4 o;
    o.x = (uint_t)f2b(acc[0] * inv) | ((uint_t)f2b(acc[1] * inv) << 16);
    o.y = (uint_t)f2b(acc[2] * inv) | ((uint_t)f2b(acc[3] * inv) << 16);
    o.z = (uint_t)f2b(acc[4] * inv) | ((uint_t)f2b(acc[5] * inv) << 16);
    o.w = (uint_t)f2b(acc[6] * inv) | ((uint_t)f2b(acc[7] * inv) << 16);
    int n = wid >> 1, r = wid & 1;
    *(uint4*)(agg + (size_t)n * 384 + r * 128 + t * 8) = o;
  }
}

// ---------------- MFMA GEMM: [M x 384] bf16 @ [384 x 128] bf16 -> f32 ------
__device__ __forceinline__ void do_mfma32(
    const char* bs, f32x4 (&acc)[4][8], const bf16x8 (&a)[4],
    int ks, int lrow, int kg) {
  bf16x8 b[8];
#pragma unroll
  for (int c = 0; c < 8; ++c)
    b[c] = *(const bf16x8*)(bs + (c * 16 + lrow) * (LDBE * 2) +
                            (ks * 4 + kg) * 16);
#pragma unroll
  for (int r = 0; r < 4; ++r)
#pragma unroll
    for (int c = 0; c < 8; ++c)
      acc[r][c] = __builtin_amdgcn_mfma_f32_16x16x32_bf16(a[r], b[c], acc[r][c], 0, 0, 0);
}

template <int MODE>
__global__ __launch_bounds__(256, 2) void mfma_gemm(
    const ushort_t* __restrict__ A,   // [Mpad][384]
    const ushort_t* __restrict__ Bt,  // [128][384]
    const float* __restrict__ bias,   // [128]
    float* __restrict__ outf,
    ushort_t* __restrict__ outb,
    int M) {
  __shared__ __align__(16) ushort_t Bs[2][128 * LDBE];  // 2 x 34816 B
  const int tid = threadIdx.x;
  const int lane = tid & 63;
  const int wave = tid >> 6;
  const int lrow = lane & 15;
  const int kg = lane >> 4;
  const int rowbase = blockIdx.x * GBM + wave * 64;

  f32x4 acc[4][8];
#pragma unroll
  for (int r = 0; r < 4; ++r)
#pragma unroll
    for (int c = 0; c < 8; ++c) acc[r][c] = (f32x4){0.f, 0.f, 0.f, 0.f};

  uint4 stg[8];
#pragma unroll
  for (int j = 0; j < 8; ++j) {
    int flat = tid + j * 256;  // 0..2047
    int col = flat >> 4;
    int q = flat & 15;
    stg[j] = *(const uint4*)(Bt + (size_t)col * 384 + q * 8);
  }
#pragma unroll
  for (int j = 0; j < 8; ++j) {
    int flat = tid + j * 256;
    int col = flat >> 4;
    int q = flat & 15;
    *(uint4*)((char*)&Bs[0][0] + col * (LDBE * 2) + q * 16) = stg[j];
  }
  __syncthreads();

  int cur = 0;
  for (int ch = 0; ch < 3; ++ch) {
    if (ch < 2) {  // issue next chunk's loads before compute
#pragma unroll
      for (int j = 0; j < 8; ++j) {
        int flat = tid + j * 256;
        int col = flat >> 4;
        int q = flat & 15;
        stg[j] = *(const uint4*)(Bt + (size_t)col * 384 + (ch + 1) * KCH + q * 8);
      }
    }
    const ushort_t* ab = A + (size_t)ch * KCH + kg * 8;
    const char* bsbase = (const char*)&Bs[0][0] + cur * (128 * LDBE * 2);
    bf16x8 aA[4], aB[4];
#pragma unroll
    for (int r = 0; r < 4; ++r)
      aA[r] = *(const bf16x8*)(ab + (size_t)(rowbase + r * 16 + lrow) * 384);
#pragma unroll
    for (int r = 0; r < 4; ++r)
      aB[r] = *(const bf16x8*)(ab + (size_t)(rowbase + r * 16 + lrow) * 384 + 32);
    do_mfma32(bsbase, acc, aA, 0, lrow, kg);
#pragma unroll
    for (int r = 0; r < 4; ++r)
      aA[r] = *(const bf16x8*)(ab + (size_t)(rowbase + r * 16 + lrow) * 384 + 64);
    do_mfma32(bsbase, acc, aB, 1, lrow, kg);
#pragma unroll
    for (int r = 0; r < 4; ++r)
      aB[r] = *(const bf16x8*)(ab + (size_t)(rowbase + r * 16 + lrow) * 384 + 96);
    do_mfma32(bsbase, acc, aA, 2, lrow, kg);
    do_mfma32(bsbase, acc, aB, 3, lrow, kg);
    if (ch < 2) {
#pragma unroll
      for (int j = 0; j < 8; ++j) {
        int flat = tid + j * 256;
        int col = flat >> 4;
        int q = flat & 15;
        *(uint4*)((char*)&Bs[0][0] + (cur ^ 1) * (128 * LDBE * 2) +
                  col * (LDBE * 2) + q * 16) = stg[j];
      }
      __syncthreads();
      cur ^= 1;
    }
  }

  // ---- epilogue
  if (MODE == 1) {
    // stage relu(acc+bias) as bf16 rows in LDS (Bs is dead), then write
    // each 256 B row with uint4 stores -> no partial-line write amp.
    __syncthreads();  // all waves done reading Bs
    ushort_t* ws = (ushort_t*)&Bs[0][0] + wave * (64 * 128);
#pragma unroll
    for (int c = 0; c < 8; ++c) {
      int col = c * 16 + lrow;
      float bv = bias[col];
#pragma unroll
      for (int r = 0; r < 4; ++r)
#pragma unroll
        for (int j = 0; j < 4; ++j) {
          float v = fmaxf(acc[r][c][j] + bv, 0.f);
          ws[(r * 16 + kg * 4 + j) * 128 + col] = f2b(v);
        }
    }
    __syncthreads();
#pragma unroll
    for (int rr = 0; rr < 16; ++rr) {
      int lr = rr * 4 + (lane >> 4);   // local row 0..63
      int row = rowbase + lr;
      int tq = lane & 15;
      if (row < M) {
        uint4 v = *(const uint4*)(ws + lr * 128 + tq * 8);
        *(uint4*)(outb + (size_t)row * 384 + 256 + tq * 8) = v;
      }
    }
  } else {
#pragma unroll
    for (int c = 0; c < 8; ++c) {
      int col = c * 16 + lrow;
      float bv = bias[col];
#pragma unroll
      for (int r = 0; r < 4; ++r) {
        int r0 = rowbase + r * 16 + kg * 4;
#pragma unroll
        for (int j = 0; j < 4; ++j) {
          int row = r0 + j;
          if (row < M) {
            outf[(size_t)row * 128 + col] = acc[r][c][j] + bv;
          }
        }
      }
    }
  }
}

// ---------------- launch ----------------
extern "C" void kernel_launch(void* const* d_in, const int* in_sizes, int n_in,
                              void* d_out, int out_size, void* d_ws, size_t ws_size,
                              hipStream_t stream) {
  const float* x     = (const float*)d_in[0];
  const int*   ea    = (const int*)d_in[1];
  const int*   eb    = (const int*)d_in[2];
  const float* W1    = (const float*)d_in[3];
  const float* root1 = (const float*)d_in[4];
  const float* b1    = (const float*)d_in[5];
  const float* W2    = (const float*)d_in[6];
  const float* root2 = (const float*)d_in[7];
  const float* b2    = (const float*)d_in[8];
  float* out = (float*)d_out;

  const int N = in_sizes[0] / 128;
  const int E = in_sizes[1] / 2;
  const int nseg = N * 2;
  const int Mblk = (N + GBM - 1) / GBM;           // 391
  const int Mpad = Mblk * GBM;                    // 100096
  const int NB = ((N - 1) >> BSHIFT) + 1;         // 196
  const int nchunk = (2 * E + CHUNK - 1) / CHUNK; // 782

  // workspace carve-up (all 16B-aligned)
  char* p = (char*)d_ws;
  ushort_t* aggbuf1 = (ushort_t*)p;  p += (size_t)Mpad * 384 * sizeof(ushort_t);
  ushort_t* aggbuf2 = (ushort_t*)p;  p += (size_t)Mpad * 384 * sizeof(ushort_t);
  ushort_t* Bt1 = (ushort_t*)p;      p += (size_t)128 * 384 * sizeof(ushort_t);
  ushort_t* Bt2 = (ushort_t*)p;      p += (size_t)128 * 384 * sizeof(ushort_t);
  int* csr = (int*)p;                p += (size_t)NBMAX * SLAB * sizeof(int);
  int* offs = (int*)p;               p += (size_t)nseg * sizeof(int);
  int* ends = (int*)p;               p += (size_t)nseg * sizeof(int);
  int* cursor = (int*)p;             p += NBMAX * sizeof(int);
  // staging (NB*SLAB uint = 12.8 MB) aliases aggbuf2 (dead until gemm1)
  uint_t* staging = (uint_t*)aggbuf2;

  hipMemsetAsync(cursor, 0, NBMAX * sizeof(int), stream);

  bucket_bin<<<nchunk, 256, 0, stream>>>(ea, eb, E, NB, cursor, staging);

  build_fused<<<NB + 96 + XSGB, 1024, 0, stream>>>(
      staging, cursor, csr, offs, ends, nseg, NB,
      W1, root1, W2, root2, Bt1, Bt2, x, aggbuf1, N);

  const int agg_blocks = (nseg + 3) / 4;  // 4 waves/block, 1 wave/segment

  // layer 1
  agg_kernel<<<agg_blocks, 256, 0, stream>>>((const char*)aggbuf1, csr, offs,
                                             ends, aggbuf1, nseg);
  mfma_gemm<1><<<Mblk, 256, 0, stream>>>(aggbuf1, Bt1, b1, nullptr, aggbuf2, N);

  // layer 2
  agg_kernel<<<agg_blocks, 256, 0, stream>>>((const char*)aggbuf2, csr, offs,
                                             ends, aggbuf2, nseg);
  mfma_gemm<0><<<Mblk, 256, 0, stream>>>(aggbuf2, Bt2, b2, out, nullptr, N);
}

// Round 15
// 280.126 us; speedup vs baseline: 1.0361x; 1.0361x over previous
//
#include <hip/hip_runtime.h>
#include <hip/hip_bf16.h>

// RGCN (2 relations, d=128, two layers) for MI355X — round 15.
// Aggregate-then-transform, bf16 MFMA GEMM (16x16x32).
//   A[n] = [mean_r0 | mean_r1 | x_n]  (384 bf16, contiguous)
//   out[n] = A[n] @ [W0; W1; root] + bias   (one fused GEMM per layer)
// Round-15 changes:
//  - REVERT r14 (xstage/Bt back inside prep_bin dispatch — overlaps bin).
//  - Both prefix scans (bin 256-wide, build 1024-wide) replaced with
//    __shfl_up wave scans: 20 block barriers -> 1 (build), 16 -> 1 (bin).

typedef __attribute__((ext_vector_type(8))) short bf16x8;
typedef __attribute__((ext_vector_type(4))) float f32x4;
typedef unsigned short ushort_t;
typedef unsigned int uint_t;

#define BSHIFT 9                      // bucket = dst >> 9 (512 nodes/bucket)
#define SEGB (1 << (BSHIFT + 1))      // 1024 segments per bucket
#define NBMAX 256
#define SLAB 16384                    // records per bucket slab (mean ~8163)
#define CH_PER_THREAD 8
#define CHUNK (256 * CH_PER_THREAD)   // 2048 edges per bin block
#define XSB 1024                      // xstage grid-stride blocks

#define GBM 256                       // GEMM rows per block
#define KCH 128                       // GEMM k per LDS chunk (3 chunks)
#define LDBE 136                      // LDS B row stride in elements (272 B)

#define ROWB 768                      // bytes per A row (384 bf16)
#define XOFF 512                      // byte offset of x-slot within row

__device__ __forceinline__ ushort_t f2b(float f) {
  union { float f; uint_t u; } v;
  v.f = f;
  uint_t u = v.u;
  return (ushort_t)((u + 0x7FFFu + ((u >> 16) & 1u)) >> 16);  // RNE
}
// acc += pk.lo*sel.lo + pk.hi*sel.hi  (bf16 pairs, f32 accumulate)
__device__ __forceinline__ void dot2acc(float& a, uint_t pk, uint_t sel) {
  asm("v_dot2_f32_bf16 %0, %1, %2, %0" : "+v"(a) : "v"(pk), "v"(sel));
}

// ---------------- prep_bin: bin chunks + Bt build + xstage in one grid ----
__global__ __launch_bounds__(256) void prep_bin(
    const int* __restrict__ ea, const int* __restrict__ eb, int E, int NB,
    int* __restrict__ cursor, uint_t* __restrict__ staging, int nchunk,
    const float* __restrict__ W1, const float* __restrict__ root1,
    const float* __restrict__ W2, const float* __restrict__ root2,
    ushort_t* __restrict__ Bt1, ushort_t* __restrict__ Bt2,
    const float* __restrict__ x, ushort_t* __restrict__ aggbuf1, int N) {
  __shared__ int h[NBMAX];
  __shared__ int bbase[NBMAX];
  __shared__ int lofs[NBMAX];
  __shared__ int wtot[4];
  __shared__ uint_t sval[CHUNK];
  __shared__ int sdst[CHUNK];
  int b = blockIdx.x;
  int t = threadIdx.x;

  if (b < nchunk) {
    // ---- bin: LDS-sorted records -> per-bucket slab runs
    for (int i = t; i < NB; i += 256) h[i] = 0;
    __syncthreads();
    int base_i = b * CHUNK + t * CH_PER_THREAD;  // 8 consecutive edges
    int total = 2 * E;
    int srcv[CH_PER_THREAD], dstv[CH_PER_THREAD], relv;
    bool valid8 = false;
    if (base_i + CH_PER_THREAD <= E) {
      int4 s0 = *(const int4*)(ea + base_i);
      int4 s1 = *(const int4*)(ea + base_i + 4);
      int4 d0 = *(const int4*)(ea + E + base_i);
      int4 d1 = *(const int4*)(ea + E + base_i + 4);
      srcv[0]=s0.x; srcv[1]=s0.y; srcv[2]=s0.z; srcv[3]=s0.w;
      srcv[4]=s1.x; srcv[5]=s1.y; srcv[6]=s1.z; srcv[7]=s1.w;
      dstv[0]=d0.x; dstv[1]=d0.y; dstv[2]=d0.z; dstv[3]=d0.w;
      dstv[4]=d1.x; dstv[5]=d1.y; dstv[6]=d1.z; dstv[7]=d1.w;
      relv = 0; valid8 = true;
    } else if (base_i >= E && base_i + CH_PER_THREAD <= total) {
      int off = base_i - E;
      int4 s0 = *(const int4*)(eb + off);
      int4 s1 = *(const int4*)(eb + off + 4);
      int4 d0 = *(const int4*)(eb + E + off);
      int4 d1 = *(const int4*)(eb + E + off + 4);
      srcv[0]=s0.x; srcv[1]=s0.y; srcv[2]=s0.z; srcv[3]=s0.w;
      srcv[4]=s1.x; srcv[5]=s1.y; srcv[6]=s1.z; srcv[7]=s1.w;
      dstv[0]=d0.x; dstv[1]=d0.y; dstv[2]=d0.z; dstv[3]=d0.w;
      dstv[4]=d1.x; dstv[5]=d1.y; dstv[6]=d1.z; dstv[7]=d1.w;
      relv = 1; valid8 = true;
    }
    uint_t val[CH_PER_THREAD];
    short bktv[CH_PER_THREAD];
    short rj[CH_PER_THREAD];
    if (valid8) {
#pragma unroll
      for (int j = 0; j < CH_PER_THREAD; ++j) {
        int seg = dstv[j] * 2 + relv;
        int bkt = seg >> (BSHIFT + 1);
        val[j] = ((uint_t)srcv[j] << 10) | (uint_t)(seg & (SEGB - 1));
        bktv[j] = (short)bkt;
        rj[j] = (short)atomicAdd(&h[bkt], 1);
      }
    } else {
#pragma unroll
      for (int j = 0; j < CH_PER_THREAD; ++j) {
        int i = base_i + j;
        if (i < total) {
          int src, dst, rel;
          if (i < E) { src = ea[i];     dst = ea[E + i]; rel = 0; }
          else       { src = eb[i - E]; dst = eb[i];     rel = 1; }
          int seg = dst * 2 + rel;
          int bkt = seg >> (BSHIFT + 1);
          val[j] = ((uint_t)src << 10) | (uint_t)(seg & (SEGB - 1));
          bktv[j] = (short)bkt;
          rj[j] = (short)atomicAdd(&h[bkt], 1);
        } else {
          bktv[j] = -1;
        }
      }
    }
    __syncthreads();
    {
      // exclusive scan of h[0..NB) via wave shfl scan (1 barrier)
      int v = (t < NB) ? h[t] : 0;
      int lane = t & 63, w = t >> 6;
      int s = v;
#pragma unroll
      for (int off = 1; off < 64; off <<= 1) {
        int u = __shfl_up(s, off);
        if (lane >= off) s += u;
      }
      if (lane == 63) wtot[w] = s;
      __syncthreads();
      int woff = 0;
#pragma unroll
      for (int i = 0; i < 4; ++i)
        if (i < w) woff += wtot[i];
      int incl = s + woff;
      if (t < NB) {
        lofs[t] = incl - v;
        bbase[t] = v ? t * SLAB + atomicAdd(&cursor[t], v) : 0;
      }
    }
    __syncthreads();
#pragma unroll
    for (int j = 0; j < CH_PER_THREAD; ++j) {
      if (!valid8 && bktv[j] < 0) continue;
      int bkt = bktv[j];
      int pos = lofs[bkt] + rj[j];
      sval[pos] = val[j];
      sdst[pos] = bbase[bkt] + rj[j];
    }
    __syncthreads();
    int nrec = 2 * E - b * CHUNK;
    if (nrec > CHUNK) nrec = CHUNK;
    for (int i = t; i < nrec; i += 256)
      staging[sdst[i]] = sval[i];
  } else if (b < nchunk + 384) {
    // ---- Bt build
    int flat = (b - nchunk) * 256 + t;       // 0..98303
    int which = flat >= 49152;
    int idx = flat - which * 49152;
    int c = idx / 384;
    int k = idx - c * 384;
    const float* W = which ? W2 : W1;
    const float* root = which ? root2 : root1;
    ushort_t* Bt = which ? Bt2 : Bt1;
    float v = (k < 256) ? W[(size_t)k * 128 + c] : root[(size_t)(k - 256) * 128 + c];
    Bt[(size_t)c * 384 + k] = f2b(v);
  } else {
    // ---- xstage: grid-stride, 16 lanes per row, uint4 per lane
    int idx = (b - nchunk - 384) * 256 + t;
    int tot = N * 16;
    int step = XSB * 256;
    for (; idx < tot; idx += step) {
      int n = idx >> 4, tq = idx & 15;
      float4 a = *(const float4*)(x + (size_t)n * 128 + tq * 8);
      float4 c = *(const float4*)(x + (size_t)n * 128 + tq * 8 + 4);
      uint4 o;
      o.x = (uint_t)f2b(a.x) | ((uint_t)f2b(a.y) << 16);
      o.y = (uint_t)f2b(a.z) | ((uint_t)f2b(a.w) << 16);
      o.z = (uint_t)f2b(c.x) | ((uint_t)f2b(c.y) << 16);
      o.w = (uint_t)f2b(c.z) | ((uint_t)f2b(c.w) << 16);
      *(uint4*)(aggbuf1 + (size_t)n * 384 + 256 + tq * 8) = o;
    }
  }
}

// ---------------- build: per-bucket seg hist + scan + scatter (1024 thr) ---
// staging read ONCE via uint4; records + ranks in registers; shfl scan.
__global__ __launch_bounds__(1024) void bucket_build(
    const uint_t* __restrict__ staging, const int* __restrict__ cursor,
    int* __restrict__ csr, int* __restrict__ offs,
    int* __restrict__ ends, int nseg) {
  __shared__ int scnt[SEGB];
  __shared__ int sexcl[SEGB];
  __shared__ int wtot[16];
  int b = blockIdx.x;
  int t = threadIdx.x;       // 0..1023, one segment counter per thread
  int base = b * SLAB;
  int ne = cursor[b];
  int seg0 = b << (BSHIFT + 1);

  scnt[t] = 0;
  __syncthreads();
  const uint_t* st = staging + base;
  uint_t rec[16];
  short rk[16];
#pragma unroll
  for (int k = 0; k < 4; ++k) {
    int i = (t + k * 1024) * 4;
    if (i + 4 <= ne) {
      uint4 v = *(const uint4*)(st + i);
      rec[k * 4 + 0] = v.x;
      rec[k * 4 + 1] = v.y;
      rec[k * 4 + 2] = v.z;
      rec[k * 4 + 3] = v.w;
#pragma unroll
      for (int j = 0; j < 4; ++j)
        rk[k * 4 + j] = (short)atomicAdd(&scnt[rec[k * 4 + j] & (SEGB - 1)], 1);
    } else {
#pragma unroll
      for (int j = 0; j < 4; ++j) {
        int i2 = i + j;
        if (i2 < ne) {
          uint_t v = st[i2];
          rec[k * 4 + j] = v;
          rk[k * 4 + j] = (short)atomicAdd(&scnt[v & (SEGB - 1)], 1);
        } else {
          rec[k * 4 + j] = 0xffffffffu;
        }
      }
    }
  }
  __syncthreads();
  int c = scnt[t];
  {
    // exclusive scan over 1024 via wave shfl scan (1 barrier)
    int lane = t & 63, w = t >> 6;
    int s = c;
#pragma unroll
    for (int off = 1; off < 64; off <<= 1) {
      int u = __shfl_up(s, off);
      if (lane >= off) s += u;
    }
    if (lane == 63) wtot[w] = s;
    __syncthreads();
    int woff = 0;
#pragma unroll
    for (int i = 0; i < 16; ++i)
      if (i < w) woff += wtot[i];
    int excl = s + woff - c;
    sexcl[t] = excl;
    int g = seg0 + t;
    if (g < nseg) { offs[g] = base + excl; ends[g] = base + excl + c; }
  }
  __syncthreads();
#pragma unroll
  for (int k = 0; k < 16; ++k) {
    if (rec[k] != 0xffffffffu) {
      int seg = (int)(rec[k] & (SEGB - 1));
      int src = (int)(rec[k] >> 10);
      csr[base + sexcl[seg] + rk[k]] = src * ROWB + XOFF;  // pre-scaled bytes
    }
  }
}

// ---------------- aggregation: one wave per segment, quarter-wave per edge --
// csr entries are byte offsets of the source row's x-slot. dot2 accumulate.
__global__ __launch_bounds__(256) void agg_kernel(
    const char* __restrict__ xbc,      // aggbuf base (bytes)
    const int* __restrict__ csr,
    const int* __restrict__ offs, const int* __restrict__ ends,
    ushort_t* __restrict__ agg, int nseg) {
  int wid = (blockIdx.x * blockDim.x + threadIdx.x) >> 6;
  if (wid >= nseg) return;
  int lane = threadIdx.x & 63;
  int q = lane >> 4;
  int t = lane & 15;
  int beg = offs[wid], end = ends[wid];
  const uint_t sel_lo = 0x00003F80u;   // bf16 (1.0, 0.0)
  const uint_t sel_hi = 0x3F800000u;   // bf16 (0.0, 1.0)

  float acc[8];
#pragma unroll
  for (int j = 0; j < 8; ++j) acc[j] = 0.f;

  const char* xt = xbc + t * 16;
  int e = beg + q;
  for (; e + 4 < end; e += 8) {
    int o0 = csr[e];
    int o1 = csr[e + 4];
    uint4 v0 = *(const uint4*)(xt + o0);
    uint4 v1 = *(const uint4*)(xt + o1);
    dot2acc(acc[0], v0.x, sel_lo); dot2acc(acc[1], v0.x, sel_hi);
    dot2acc(acc[2], v0.y, sel_lo); dot2acc(acc[3], v0.y, sel_hi);
    dot2acc(acc[4], v0.z, sel_lo); dot2acc(acc[5], v0.z, sel_hi);
    dot2acc(acc[6], v0.w, sel_lo); dot2acc(acc[7], v0.w, sel_hi);
    dot2acc(acc[0], v1.x, sel_lo); dot2acc(acc[1], v1.x, sel_hi);
    dot2acc(acc[2], v1.y, sel_lo); dot2acc(acc[3], v1.y, sel_hi);
    dot2acc(acc[4], v1.z, sel_lo); dot2acc(acc[5], v1.z, sel_hi);
    dot2acc(acc[6], v1.w, sel_lo); dot2acc(acc[7], v1.w, sel_hi);
  }
  if (e < end) {
    int o0 = csr[e];
    uint4 v0 = *(const uint4*)(xt + o0);
    dot2acc(acc[0], v0.x, sel_lo); dot2acc(acc[1], v0.x, sel_hi);
    dot2acc(acc[2], v0.y, sel_lo); dot2acc(acc[3], v0.y, sel_hi);
    dot2acc(acc[4], v0.z, sel_lo); dot2acc(acc[5], v0.z, sel_hi);
    dot2acc(acc[6], v0.w, sel_lo); dot2acc(acc[7], v0.w, sel_hi);
  }

#pragma unroll
  for (int j = 0; j < 8; ++j) {
    acc[j] += __shfl_xor(acc[j], 16);
    acc[j] += __shfl_xor(acc[j], 32);
  }

  int c = end - beg;
  float inv = 1.0f / (float)(c > 1 ? c : 1);
  if (q == 0) {
    uint4 o;
    o.x = (uint_t)f2b(acc[0] * inv) | ((uint_t)f2b(acc[1] * inv) << 16);
    o.y = (uint_t)f2b(acc[2] * inv) | ((uint_t)f2b(acc[3] * inv) << 16);
    o.z = (uint_t)f2b(acc[4] * inv) | ((uint_t)f2b(acc[5] * inv) << 16);
    o.w = (uint_t)f2b(acc[6] * inv) | ((uint_t)f2b(acc[7] * inv) << 16);
    int n = wid >> 1, r = wid & 1;
    *(uint4*)(agg + (size_t)n * 384 + r * 128 + t * 8) = o;
  }
}

// ---------------- MFMA GEMM: [M x 384] bf16 @ [384 x 128] bf16 -> f32 ------
__device__ __forceinline__ void do_mfma32(
    const char* bs, f32x4 (&acc)[4][8], const bf16x8 (&a)[4],
    int ks, int lrow, int kg) {
  bf16x8 b[8];
#pragma unroll
  for (int c = 0; c < 8; ++c)
    b[c] = *(const bf16x8*)(bs + (c * 16 + lrow) * (LDBE * 2) +
                            (ks * 4 + kg) * 16);
#pragma unroll
  for (int r = 0; r < 4; ++r)
#pragma unroll
    for (int c = 0; c < 8; ++c)
      acc[r][c] = __builtin_amdgcn_mfma_f32_16x16x32_bf16(a[r], b[c], acc[r][c], 0, 0, 0);
}

template <int MODE>
__global__ __launch_bounds__(256, 2) void mfma_gemm(
    const ushort_t* __restrict__ A,   // [Mpad][384]
    const ushort_t* __restrict__ Bt,  // [128][384]
    const float* __restrict__ bias,   // [128]
    float* __restrict__ outf,
    ushort_t* __restrict__ outb,
    int M) {
  __shared__ __align__(16) ushort_t Bs[2][128 * LDBE];  // 2 x 34816 B
  const int tid = threadIdx.x;
  const int lane = tid & 63;
  const int wave = tid >> 6;
  const int lrow = lane & 15;
  const int kg = lane >> 4;
  const int rowbase = blockIdx.x * GBM + wave * 64;

  f32x4 acc[4][8];
#pragma unroll
  for (int r = 0; r < 4; ++r)
#pragma unroll
    for (int c = 0; c < 8; ++c) acc[r][c] = (f32x4){0.f, 0.f, 0.f, 0.f};

  uint4 stg[8];
#pragma unroll
  for (int j = 0; j < 8; ++j) {
    int flat = tid + j * 256;  // 0..2047
    int col = flat >> 4;
    int q = flat & 15;
    stg[j] = *(const uint4*)(Bt + (size_t)col * 384 + q * 8);
  }
#pragma unroll
  for (int j = 0; j < 8; ++j) {
    int flat = tid + j * 256;
    int col = flat >> 4;
    int q = flat & 15;
    *(uint4*)((char*)&Bs[0][0] + col * (LDBE * 2) + q * 16) = stg[j];
  }
  __syncthreads();

  int cur = 0;
  for (int ch = 0; ch < 3; ++ch) {
    if (ch < 2) {  // issue next chunk's loads before compute
#pragma unroll
      for (int j = 0; j < 8; ++j) {
        int flat = tid + j * 256;
        int col = flat >> 4;
        int q = flat & 15;
        stg[j] = *(const uint4*)(Bt + (size_t)col * 384 + (ch + 1) * KCH + q * 8);
      }
    }
    const ushort_t* ab = A + (size_t)ch * KCH + kg * 8;
    const char* bsbase = (const char*)&Bs[0][0] + cur * (128 * LDBE * 2);
    bf16x8 aA[4], aB[4];
#pragma unroll
    for (int r = 0; r < 4; ++r)
      aA[r] = *(const bf16x8*)(ab + (size_t)(rowbase + r * 16 + lrow) * 384);
#pragma unroll
    for (int r = 0; r < 4; ++r)
      aB[r] = *(const bf16x8*)(ab + (size_t)(rowbase + r * 16 + lrow) * 384 + 32);
    do_mfma32(bsbase, acc, aA, 0, lrow, kg);
#pragma unroll
    for (int r = 0; r < 4; ++r)
      aA[r] = *(const bf16x8*)(ab + (size_t)(rowbase + r * 16 + lrow) * 384 + 64);
    do_mfma32(bsbase, acc, aB, 1, lrow, kg);
#pragma unroll
    for (int r = 0; r < 4; ++r)
      aB[r] = *(const bf16x8*)(ab + (size_t)(rowbase + r * 16 + lrow) * 384 + 96);
    do_mfma32(bsbase, acc, aA, 2, lrow, kg);
    do_mfma32(bsbase, acc, aB, 3, lrow, kg);
    if (ch < 2) {
#pragma unroll
      for (int j = 0; j < 8; ++j) {
        int flat = tid + j * 256;
        int col = flat >> 4;
        int q = flat & 15;
        *(uint4*)((char*)&Bs[0][0] + (cur ^ 1) * (128 * LDBE * 2) +
                  col * (LDBE * 2) + q * 16) = stg[j];
      }
      __syncthreads();
      cur ^= 1;
    }
  }

  // ---- epilogue
  if (MODE == 1) {
    // stage relu(acc+bias) as bf16 rows in LDS (Bs is dead), then write
    // each 256 B row with uint4 stores -> no partial-line write amp.
    __syncthreads();  // all waves done reading Bs
    ushort_t* ws = (ushort_t*)&Bs[0][0] + wave * (64 * 128);
#pragma unroll
    for (int c = 0; c < 8; ++c) {
      int col = c * 16 + lrow;
      float bv = bias[col];
#pragma unroll
      for (int r = 0; r < 4; ++r)
#pragma unroll
        for (int j = 0; j < 4; ++j) {
          float v = fmaxf(acc[r][c][j] + bv, 0.f);
          ws[(r * 16 + kg * 4 + j) * 128 + col] = f2b(v);
        }
    }
    __syncthreads();
#pragma unroll
    for (int rr = 0; rr < 16; ++rr) {
      int lr = rr * 4 + (lane >> 4);   // local row 0..63
      int row = rowbase + lr;
      int tq = lane & 15;
      if (row < M) {
        uint4 v = *(const uint4*)(ws + lr * 128 + tq * 8);
        *(uint4*)(outb + (size_t)row * 384 + 256 + tq * 8) = v;
      }
    }
  } else {
#pragma unroll
    for (int c = 0; c < 8; ++c) {
      int col = c * 16 + lrow;
      float bv = bias[col];
#pragma unroll
      for (int r = 0; r < 4; ++r) {
        int r0 = rowbase + r * 16 + kg * 4;
#pragma unroll
        for (int j = 0; j < 4; ++j) {
          int row = r0 + j;
          if (row < M) {
            outf[(size_t)row * 128 + col] = acc[r][c][j] + bv;
          }
        }
      }
    }
  }
}

// ---------------- launch ----------------
extern "C" void kernel_launch(void* const* d_in, const int* in_sizes, int n_in,
                              void* d_out, int out_size, void* d_ws, size_t ws_size,
                              hipStream_t stream) {
  const float* x     = (const float*)d_in[0];
  const int*   ea    = (const int*)d_in[1];
  const int*   eb    = (const int*)d_in[2];
  const float* W1    = (const float*)d_in[3];
  const float* root1 = (const float*)d_in[4];
  const float* b1    = (const float*)d_in[5];
  const float* W2    = (const float*)d_in[6];
  const float* root2 = (const float*)d_in[7];
  const float* b2    = (const float*)d_in[8];
  float* out = (float*)d_out;

  const int N = in_sizes[0] / 128;
  const int E = in_sizes[1] / 2;
  const int nseg = N * 2;
  const int Mblk = (N + GBM - 1) / GBM;           // 391
  const int Mpad = Mblk * GBM;                    // 100096
  const int NB = ((N - 1) >> BSHIFT) + 1;         // 196
  const int nchunk = (2 * E + CHUNK - 1) / CHUNK; // 782

  // workspace carve-up (all 16B-aligned)
  char* p = (char*)d_ws;
  ushort_t* aggbuf1 = (ushort_t*)p;  p += (size_t)Mpad * 384 * sizeof(ushort_t);
  ushort_t* aggbuf2 = (ushort_t*)p;  p += (size_t)Mpad * 384 * sizeof(ushort_t);
  ushort_t* Bt1 = (ushort_t*)p;      p += (size_t)128 * 384 * sizeof(ushort_t);
  ushort_t* Bt2 = (ushort_t*)p;      p += (size_t)128 * 384 * sizeof(ushort_t);
  int* csr = (int*)p;                p += (size_t)NBMAX * SLAB * sizeof(int);
  int* offs = (int*)p;               p += (size_t)nseg * sizeof(int);
  int* ends = (int*)p;               p += (size_t)nseg * sizeof(int);
  int* cursor = (int*)p;             p += NBMAX * sizeof(int);
  // staging (NB*SLAB uint = 12.8 MB) aliases aggbuf2 (dead until gemm1)
  uint_t* staging = (uint_t*)aggbuf2;

  hipMemsetAsync(cursor, 0, NBMAX * sizeof(int), stream);

  prep_bin<<<nchunk + 384 + XSB, 256, 0, stream>>>(
      ea, eb, E, NB, cursor, staging, nchunk,
      W1, root1, W2, root2, Bt1, Bt2, x, aggbuf1, N);

  bucket_build<<<NB, 1024, 0, stream>>>(staging, cursor, csr, offs, ends, nseg);

  const int agg_blocks = (nseg + 3) / 4;  // 4 waves/block, 1 wave/segment

  // layer 1
  agg_kernel<<<agg_blocks, 256, 0, stream>>>((const char*)aggbuf1, csr, offs,
                                             ends, aggbuf1, nseg);
  mfma_gemm<1><<<Mblk, 256, 0, stream>>>(aggbuf1, Bt1, b1, nullptr, aggbuf2, N);

  // layer 2
  agg_kernel<<<agg_blocks, 256, 0, stream>>>((const char*)aggbuf2, csr, offs,
                                             ends, aggbuf2, nseg);
  mfma_gemm<0><<<Mblk, 256, 0, stream>>>(aggbuf2, Bt2, b2, out, nullptr, N);
}